// Round 11
// baseline (298.325 us; speedup 1.0000x reference)
//
#include <hip/hip_runtime.h>
#include <hip/hip_bf16.h>

#define BB 2
#define SS 2048
#define DIMM 1024
#define HH 16
#define DKK 64
// 0.125 (1/sqrt(DK)) * log2(e): folded into Q so softmax uses raw v_exp_f32 (2^x)
#define QSCALE 0.18033688011112042592f

using bf16 = __hip_bfloat16;
typedef __attribute__((ext_vector_type(8))) short v8s;
typedef __attribute__((ext_vector_type(4))) short v4s;
typedef __attribute__((ext_vector_type(4))) float f32x4;

// async global->LDS 16B copy: LDS dest = wave-uniform base + lane*16
__device__ __forceinline__ void gl2lds16(const bf16* g, bf16* l) {
  __builtin_amdgcn_global_load_lds(
      (const __attribute__((address_space(1))) void*)g,
      (__attribute__((address_space(3))) void*)l, 16, 0, 0);
}

__device__ __forceinline__ void cvt4(const float* __restrict__ s,
                                     bf16* __restrict__ d, int idx) {
  const float4 f = ((const float4*)s)[idx];
  bf16 t[4] = {__float2bfloat16(f.x), __float2bfloat16(f.y),
               __float2bfloat16(f.z), __float2bfloat16(f.w)};
  *(v4s*)(d + (size_t)idx * 4) = *(const v4s*)t;
}

// ---------------------------------------------------------------------------
// Fused fp32->bf16 conversion (dec, enc, Wq, Wkv, Wo) + mask bit-packing.
// decb/Wqb live in d_out (dead scratch until out_gemm overwrites it).
// ---------------------------------------------------------------------------
__global__ __launch_bounds__(256) void convert_pack_kernel(
    const float* __restrict__ dec, const float* __restrict__ enc,
    const float* __restrict__ Wq, const float* __restrict__ Wkv,
    const float* __restrict__ Wo, const int* __restrict__ mask,
    bf16* __restrict__ decb, bf16* __restrict__ encb, bf16* __restrict__ Wqb,
    bf16* __restrict__ Wkvb, bf16* __restrict__ Wob,
    unsigned long long* __restrict__ mp) {
  const int gid = blockIdx.x * 256 + threadIdx.x;  // 0..262143
  const int NT = 256 * 1024;
#pragma unroll
  for (int i = 0; i < 4; ++i) cvt4(dec, decb, gid + i * NT);
#pragma unroll
  for (int i = 0; i < 4; ++i) cvt4(enc, encb, gid + i * NT);
  cvt4(Wq, Wqb, gid);
#pragma unroll
  for (int i = 0; i < 2; ++i) cvt4(Wkv, Wkvb, gid + i * NT);
  cvt4(Wo, Wob, gid);
  const int lane = threadIdx.x & 63;
  const int wave_id = gid >> 6;  // 0..4095
  for (int i = 0; i < 32; ++i) {
    const size_t w = (size_t)wave_id * 32 + i;
    const unsigned long long bm = __ballot(mask[w * 64 + lane] != 0);
    if (lane == 0) mp[w] = bm;
  }
}

// ---------------------------------------------------------------------------
// Merged projection GEMM, m97 pattern: 128x128 tile, BK=64, UNPADDED LDS,
// global_load_lds width-16 staging, ds_read_b128 frags, 2-barrier K-loop.
// Grid (24, 32): bx>>3 = 0 -> Q, 1 -> K, 2 -> V.  W rows index-permuted so
// output col n' = h*64+d.  Q/K store flat [b,s,h,d]; V scatters to [b,h,d,s].
// ---------------------------------------------------------------------------
__global__ __launch_bounds__(256) void proj_gemm_kernel(
    const bf16* __restrict__ decb, const bf16* __restrict__ encb,
    const bf16* __restrict__ Wqb, const bf16* __restrict__ Wkvb,
    bf16* __restrict__ Qr, bf16* __restrict__ Kr, bf16* __restrict__ Vt) {
  __shared__ __align__(16) bf16 As[128 * 64];
  __shared__ __align__(16) bf16 Bs[128 * 64];
  const int t = threadIdx.x;
  const int wave = t >> 6, lane = t & 63;
  const int quad = lane >> 4, l15 = lane & 15;
  const int wm = (wave >> 1) * 64, wn = (wave & 1) * 64;
  const int bx = blockIdx.x;
  const int kind = bx >> 3;  // 0=Q, 1=K, 2=V
  const int g = bx & 7;      // 128-col group (2 heads)
  const int m0 = blockIdx.y * 128;
  const int voff = (kind == 2) ? DIMM : 0;

  const bf16* Asrc = (kind == 0) ? decb : encb;
  const bf16* Wsrc = (kind == 0) ? Wqb : Wkvb;

  const int lr = lane >> 3;        // 0..7 row within 8-row chunk
  const int lc = (lane & 7) * 8;   // 16B column segment (8 bf16)

  f32x4 acc[4][4] = {};

  for (int kc = 0; kc < DIMM; kc += 64) {
    __syncthreads();
#pragma unroll
    for (int j = 0; j < 4; ++j) {
      const int tr = wave * 32 + j * 8 + lr;  // tile row 0..127
      gl2lds16(Asrc + (size_t)(m0 + tr) * DIMM + kc + lc,
               &As[(wave * 4 + j) * 512]);
      const int wr = (tr & 63) * 16 + g * 2 + (tr >> 6) + voff;
      gl2lds16(Wsrc + (size_t)wr * DIMM + kc + lc,
               &Bs[(wave * 4 + j) * 512]);
    }
    __syncthreads();

#pragma unroll
    for (int ks = 0; ks < 2; ++ks) {
      v8s af[4], bfr[4];
#pragma unroll
      for (int i = 0; i < 4; ++i)
        af[i] = *(const v8s*)&As[(wm + i * 16 + l15) * 64 + ks * 32 + quad * 8];
#pragma unroll
      for (int j = 0; j < 4; ++j)
        bfr[j] =
            *(const v8s*)&Bs[(wn + j * 16 + l15) * 64 + ks * 32 + quad * 8];
#pragma unroll
      for (int i = 0; i < 4; ++i)
#pragma unroll
        for (int j = 0; j < 4; ++j)
          acc[i][j] = __builtin_amdgcn_mfma_f32_16x16x32_bf16(
              af[i], bfr[j], acc[i][j], 0, 0, 0);
    }
  }

#pragma unroll
  for (int i = 0; i < 4; ++i) {
#pragma unroll
    for (int r = 0; r < 4; ++r) {
      const int m = m0 + wm + i * 16 + quad * 4 + r;
#pragma unroll
      for (int j = 0; j < 4; ++j) {
        const int c = wn + j * 16 + l15;
        const int np = g * 128 + c;  // head-contiguous col h*64+d
        const float v = acc[i][j][r];
        if (kind == 0) {
          Qr[(size_t)m * DIMM + np] = __float2bfloat16(v * QSCALE);
        } else if (kind == 1) {
          Kr[(size_t)m * DIMM + np] = __float2bfloat16(v);
        } else {
          const int h = np >> 6, d = np & 63;
          const int b = m >> 11, s = m & (SS - 1);
          Vt[(((size_t)b * HH + h) * DKK + d) * SS + s] = __float2bfloat16(v);
        }
      }
    }
  }
}

// ---------------------------------------------------------------------------
// Output projection GEMM: out = Ar @ Wob^T. m97 pattern, 128m x 64n tile,
// BK=64, global_load_lds staging, unpadded LDS.  Grid (16,32) = 512 blocks.
// ---------------------------------------------------------------------------
__global__ __launch_bounds__(256) void out_gemm_kernel(
    const bf16* __restrict__ A, const bf16* __restrict__ W,
    float* __restrict__ out) {
  __shared__ __align__(16) bf16 As[128 * 64];
  __shared__ __align__(16) bf16 Bs[64 * 64];
  const int t = threadIdx.x;
  const int wave = t >> 6, lane = t & 63;
  const int quad = lane >> 4, l15 = lane & 15;
  const int wm = (wave >> 1) * 64, wn = (wave & 1) * 32;
  const int n0 = blockIdx.x * 64;
  const int m0 = blockIdx.y * 128;

  const int lr = lane >> 3;
  const int lc = (lane & 7) * 8;

  f32x4 acc[4][2] = {};

  for (int kc = 0; kc < DIMM; kc += 64) {
    __syncthreads();
#pragma unroll
    for (int j = 0; j < 4; ++j) {
      const int tr = wave * 32 + j * 8 + lr;  // 0..127
      gl2lds16(A + (size_t)(m0 + tr) * DIMM + kc + lc,
               &As[(wave * 4 + j) * 512]);
    }
#pragma unroll
    for (int j = 0; j < 2; ++j) {
      const int tr = wave * 16 + j * 8 + lr;  // 0..63
      gl2lds16(W + (size_t)(n0 + tr) * DIMM + kc + lc,
               &Bs[(wave * 2 + j) * 512]);
    }
    __syncthreads();

#pragma unroll
    for (int ks = 0; ks < 2; ++ks) {
      v8s af[4], bfr[2];
#pragma unroll
      for (int i = 0; i < 4; ++i)
        af[i] = *(const v8s*)&As[(wm + i * 16 + l15) * 64 + ks * 32 + quad * 8];
#pragma unroll
      for (int j = 0; j < 2; ++j)
        bfr[j] =
            *(const v8s*)&Bs[(wn + j * 16 + l15) * 64 + ks * 32 + quad * 8];
#pragma unroll
      for (int i = 0; i < 4; ++i)
#pragma unroll
        for (int j = 0; j < 2; ++j)
          acc[i][j] = __builtin_amdgcn_mfma_f32_16x16x32_bf16(
              af[i], bfr[j], acc[i][j], 0, 0, 0);
    }
  }

#pragma unroll
  for (int i = 0; i < 4; ++i) {
#pragma unroll
    for (int r = 0; r < 4; ++r) {
      const int m = m0 + wm + i * 16 + quad * 4 + r;
#pragma unroll
      for (int j = 0; j < 2; ++j) {
        const int n = n0 + wn + j * 16 + l15;
        out[(size_t)m * DIMM + n] = acc[i][j][r];
      }
    }
  }
}

// ---------------------------------------------------------------------------
// MFMA flash attention (round-9 body, known 93.5 us). Q/K flat [b,s,h,d];
// Vt [b,h,d,s]. Static-max softmax, packed u64 mask (pre-shifted by l15),
// XCD swizzle.  Ar bf16 [B,S,DIM] (q, d*16+h).
// ---------------------------------------------------------------------------
__global__ __launch_bounds__(256) void attn_kernel(
    const bf16* __restrict__ Qr, const bf16* __restrict__ Kr,
    const bf16* __restrict__ Vt, const unsigned long long* __restrict__ mp,
    bf16* __restrict__ Ar) {
  __shared__ __align__(16) bf16 Ks[64][72];
  __shared__ __align__(16) bf16 Vs[64][72];  // Vs[d][kk]
  __shared__ __align__(16) bf16 Ps[4][16][72];

  const int t = threadIdx.x;
  const int wave = t >> 6, lane = t & 63;
  const int quad = lane >> 4, l15 = lane & 15;

  const int bx = blockIdx.x;
  const int xcd = bx & 7, j = bx >> 3;
  const int g = (xcd << 2) | (j & 3);  // (b,h) group 0..31
  const int tile = j >> 2;             // q-tile 0..31
  const int h = g & 15, b = g >> 4;

  const int qw = tile * 64 + wave * 16;
  const size_t bhv = ((size_t)b * HH + h) * DKK;

  const bf16* qrow = Qr + ((size_t)(b * SS + qw + l15)) * DIMM + h * 64;
  const v8s aq0 = *(const v8s*)(qrow + quad * 8);
  const v8s aq1 = *(const v8s*)(qrow + 32 + quad * 8);

  f32x4 o[4] = {};
  float lsum[4] = {0.f, 0.f, 0.f, 0.f};

  const int id0 = t * 8;
  const int r0 = id0 >> 6, c0 = id0 & 63;

  for (int kt = 0; kt < 32; ++kt) {
    const int k0 = kt * 64;
    __syncthreads();
    {
      const bf16* kb = Kr + ((size_t)(b * SS + k0 + r0)) * DIMM + h * 64 + c0;
      *(v8s*)&Ks[r0][c0] = *(const v8s*)kb;
      *(v8s*)&Ks[r0 + 32][c0] = *(const v8s*)(kb + (size_t)32 * DIMM);
      *(v8s*)&Vs[r0][c0] = *(const v8s*)(Vt + (bhv + r0) * SS + k0 + c0);
      *(v8s*)&Vs[r0 + 32][c0] =
          *(const v8s*)(Vt + (bhv + r0 + 32) * SS + k0 + c0);
    }
    __syncthreads();

    unsigned long long mw[4];
#pragma unroll
    for (int r = 0; r < 4; ++r)
      mw[r] = mp[((size_t)b * SS + qw + quad * 4 + r) * 32 + kt] >> l15;

    f32x4 sc[4];
#pragma unroll
    for (int n = 0; n < 4; ++n) {
      const v8s bk0 = *(const v8s*)&Ks[n * 16 + l15][quad * 8];
      const v8s bk1 = *(const v8s*)&Ks[n * 16 + l15][32 + quad * 8];
      f32x4 z = {0.f, 0.f, 0.f, 0.f};
      z = __builtin_amdgcn_mfma_f32_16x16x32_bf16(aq0, bk0, z, 0, 0, 0);
      sc[n] = __builtin_amdgcn_mfma_f32_16x16x32_bf16(aq1, bk1, z, 0, 0, 0);
    }

#pragma unroll
    for (int n = 0; n < 4; ++n)
#pragma unroll
      for (int r = 0; r < 4; ++r) {
        const bool keep = (mw[r] >> (n * 16)) & 1ULL;
        const float p = keep ? __builtin_amdgcn_exp2f(sc[n][r]) : 0.f;
        sc[n][r] = p;
        lsum[r] += p;
      }

    // P: C-layout -> LDS -> A-layout (per-wave region, in-wave ordering)
#pragma unroll
    for (int n = 0; n < 4; ++n)
#pragma unroll
      for (int r = 0; r < 4; ++r)
        Ps[wave][quad * 4 + r][n * 16 + l15] = __float2bfloat16(sc[n][r]);
    const v8s ap0 = *(const v8s*)&Ps[wave][l15][quad * 8];
    const v8s ap1 = *(const v8s*)&Ps[wave][l15][32 + quad * 8];

#pragma unroll
    for (int n = 0; n < 4; ++n) {
      const v8s bv0 = *(const v8s*)&Vs[n * 16 + l15][quad * 8];
      const v8s bv1 = *(const v8s*)&Vs[n * 16 + l15][32 + quad * 8];
      o[n] = __builtin_amdgcn_mfma_f32_16x16x32_bf16(ap0, bv0, o[n], 0, 0, 0);
      o[n] = __builtin_amdgcn_mfma_f32_16x16x32_bf16(ap1, bv1, o[n], 0, 0, 0);
    }
  }

#pragma unroll
  for (int r = 0; r < 4; ++r) {
    float l = lsum[r];
    l += __shfl_xor(l, 1);
    l += __shfl_xor(l, 2);
    l += __shfl_xor(l, 4);
    l += __shfl_xor(l, 8);
    const float inv = 1.f / l;
    const size_t row = (size_t)b * SS + qw + quad * 4 + r;
#pragma unroll
    for (int n = 0; n < 4; ++n) {
      const int d = n * 16 + l15;
      Ar[row * DIMM + d * 16 + h] = __float2bfloat16(o[n][r] * inv);
    }
  }
}

extern "C" void kernel_launch(void* const* d_in, const int* in_sizes, int n_in,
                              void* d_out, int out_size, void* d_ws,
                              size_t ws_size, hipStream_t stream) {
  const float* dec = (const float*)d_in[0];
  const float* enc = (const float*)d_in[1];
  const float* Wq = (const float*)d_in[2];
  const float* Wkv = (const float*)d_in[3];
  const float* Wo = (const float*)d_in[4];
  const int* mask = (const int*)d_in[5];
  float* out = (float*)d_out;

  // decb/Wqb live in d_out: dead scratch until out_gemm overwrites it.
  bf16* decb = (bf16*)d_out;
  bf16* Wqb = (bf16*)((char*)d_out + ((size_t)2 * SS * DIMM * 2));

  // ws layout (40.4 MB): encb 8 MiB (Ar overlays) | Wkvb 4 | Wob 2 |
  // Qr 8 | Kr 8 | Vt 8 | mp 1
  char* ws = (char*)d_ws;
  size_t off = 0;
  bf16* encb = (bf16*)(ws + off);
  bf16* Ar = (bf16*)(ws + off);   off += (size_t)2 * SS * DIMM * 2;
  bf16* Wkvb = (bf16*)(ws + off); off += (size_t)2 * DIMM * DIMM * 2;
  bf16* Wob = (bf16*)(ws + off);  off += (size_t)DIMM * DIMM * 2;
  bf16* Qr = (bf16*)(ws + off);   off += (size_t)2 * SS * DIMM * 2;
  bf16* Kr = (bf16*)(ws + off);   off += (size_t)2 * SS * DIMM * 2;
  bf16* Vt = (bf16*)(ws + off);   off += (size_t)2 * SS * DIMM * 2;
  unsigned long long* mp = (unsigned long long*)(ws + off);

  dim3 blk(256);
  convert_pack_kernel<<<dim3(1024), blk, 0, stream>>>(
      dec, enc, Wq, Wkv, Wo, mask, decb, encb, Wqb, Wkvb, Wob, mp);
  proj_gemm_kernel<<<dim3(24, 32), blk, 0, stream>>>(decb, encb, Wqb, Wkvb, Qr,
                                                     Kr, Vt);
  attn_kernel<<<dim3(1024), blk, 0, stream>>>(Qr, Kr, Vt, mp, Ar);
  out_gemm_kernel<<<dim3(16, 32), blk, 0, stream>>>(Ar, Wob, out);
}

// Round 12
// 282.796 us; speedup vs baseline: 1.0549x; 1.0549x over previous
//
#include <hip/hip_runtime.h>
#include <hip/hip_bf16.h>

#define BB 2
#define SS 2048
#define DIMM 1024
#define HH 16
#define DKK 64
// 0.125 (1/sqrt(DK)) * log2(e): folded into Q so softmax uses raw v_exp_f32 (2^x)
#define QSCALE 0.18033688011112042592f

using bf16 = __hip_bfloat16;
typedef __attribute__((ext_vector_type(8))) short v8s;
typedef __attribute__((ext_vector_type(4))) short v4s;
typedef __attribute__((ext_vector_type(4))) float f32x4;

__device__ __forceinline__ void cvt4(const float* __restrict__ s,
                                     bf16* __restrict__ d, int idx) {
  const float4 f = ((const float4*)s)[idx];
  bf16 t[4] = {__float2bfloat16(f.x), __float2bfloat16(f.y),
               __float2bfloat16(f.z), __float2bfloat16(f.w)};
  *(v4s*)(d + (size_t)idx * 4) = *(const v4s*)t;
}

// ---------------------------------------------------------------------------
// Fused fp32->bf16 conversion (dec, enc, Wq, Wkv, Wo) + mask bit-packing.
// decb/Wqb live in d_out (dead scratch until out_gemm overwrites it).
// ---------------------------------------------------------------------------
__global__ __launch_bounds__(256) void convert_pack_kernel(
    const float* __restrict__ dec, const float* __restrict__ enc,
    const float* __restrict__ Wq, const float* __restrict__ Wkv,
    const float* __restrict__ Wo, const int* __restrict__ mask,
    bf16* __restrict__ decb, bf16* __restrict__ encb, bf16* __restrict__ Wqb,
    bf16* __restrict__ Wkvb, bf16* __restrict__ Wob,
    unsigned long long* __restrict__ mp) {
  const int gid = blockIdx.x * 256 + threadIdx.x;  // 0..262143
  const int NT = 256 * 1024;
#pragma unroll
  for (int i = 0; i < 4; ++i) cvt4(dec, decb, gid + i * NT);
#pragma unroll
  for (int i = 0; i < 4; ++i) cvt4(enc, encb, gid + i * NT);
  cvt4(Wq, Wqb, gid);
#pragma unroll
  for (int i = 0; i < 2; ++i) cvt4(Wkv, Wkvb, gid + i * NT);
  cvt4(Wo, Wob, gid);
  const int lane = threadIdx.x & 63;
  const int wave_id = gid >> 6;  // 0..4095
  for (int i = 0; i < 32; ++i) {
    const size_t w = (size_t)wave_id * 32 + i;
    const unsigned long long bm = __ballot(mask[w * 64 + lane] != 0);
    if (lane == 0) mp[w] = bm;
  }
}

// ---------------------------------------------------------------------------
// Merged projection GEMM (round-9 reg-dbuf version — proven best at this
// shape; m97 global_load_lds variant regressed 11us, see R11 post-mortem).
// Tile 128m x 128n, BK=64.  Grid (24, 32): bx>>3 = 0 -> Q, 1 -> K, 2 -> V.
// W rows index-permuted so output col n' = h*64+d.  Q/K store flat [b,s,h,d];
// V scatters to [b,h,d,s].
// ---------------------------------------------------------------------------
__global__ __launch_bounds__(256) void proj_gemm_kernel(
    const bf16* __restrict__ decb, const bf16* __restrict__ encb,
    const bf16* __restrict__ Wqb, const bf16* __restrict__ Wkvb,
    bf16* __restrict__ Qr, bf16* __restrict__ Kr, bf16* __restrict__ Vt) {
  __shared__ __align__(16) bf16 As[128][72];
  __shared__ __align__(16) bf16 Bs[128][72];
  const int t = threadIdx.x;
  const int wave = t >> 6, lane = t & 63;
  const int quad = lane >> 4, l15 = lane & 15;
  const int wm = (wave >> 1) * 64, wn = (wave & 1) * 64;
  const int bx = blockIdx.x;
  const int kind = bx >> 3;  // 0=Q, 1=K, 2=V
  const int g = bx & 7;      // 128-col group (2 heads)
  const int m0 = blockIdx.y * 128;

  const bf16* Asrc = (kind == 0) ? decb : encb;
  const bf16* Wsrc = (kind == 0) ? Wqb : Wkvb;

  const int sr = t >> 2;        // staging row 0..63 (and +64)
  const int sc = (t & 3) * 16;  // staging col segment
  const int wr0 = sr * 16 + g * 2 + ((kind == 2) ? DIMM : 0);      // row sr
  const int wr1 = sr * 16 + g * 2 + 1 + ((kind == 2) ? DIMM : 0);  // row sr+64

  v8s apf[4], bpf[4];
  auto loadA = [&](int kc) {
    const bf16* p0 = Asrc + (size_t)(m0 + sr) * DIMM + kc + sc;
    apf[0] = ((const v8s*)p0)[0];
    apf[1] = ((const v8s*)p0)[1];
    const bf16* p1 = Asrc + (size_t)(m0 + sr + 64) * DIMM + kc + sc;
    apf[2] = ((const v8s*)p1)[0];
    apf[3] = ((const v8s*)p1)[1];
  };
  auto loadB = [&](int kc) {
    const bf16* q0 = Wsrc + (size_t)wr0 * DIMM + kc + sc;
    bpf[0] = ((const v8s*)q0)[0];
    bpf[1] = ((const v8s*)q0)[1];
    const bf16* q1 = Wsrc + (size_t)wr1 * DIMM + kc + sc;
    bpf[2] = ((const v8s*)q1)[0];
    bpf[3] = ((const v8s*)q1)[1];
  };

  f32x4 acc[4][4] = {};
  loadA(0);
  loadB(0);

  for (int kc = 0; kc < DIMM; kc += 64) {
    __syncthreads();
    *(v8s*)&As[sr][sc] = apf[0];
    *(v8s*)&As[sr][sc + 8] = apf[1];
    *(v8s*)&As[sr + 64][sc] = apf[2];
    *(v8s*)&As[sr + 64][sc + 8] = apf[3];
    *(v8s*)&Bs[sr][sc] = bpf[0];
    *(v8s*)&Bs[sr][sc + 8] = bpf[1];
    *(v8s*)&Bs[sr + 64][sc] = bpf[2];
    *(v8s*)&Bs[sr + 64][sc + 8] = bpf[3];
    if (kc + 64 < DIMM) {
      loadA(kc + 64);
      loadB(kc + 64);
    }
    __syncthreads();
#pragma unroll
    for (int ks = 0; ks < 2; ++ks) {
      v8s af[4], bfr[4];
#pragma unroll
      for (int i = 0; i < 4; ++i)
        af[i] = *(const v8s*)&As[wm + i * 16 + l15][ks * 32 + quad * 8];
#pragma unroll
      for (int j = 0; j < 4; ++j)
        bfr[j] = *(const v8s*)&Bs[wn + j * 16 + l15][ks * 32 + quad * 8];
#pragma unroll
      for (int i = 0; i < 4; ++i)
#pragma unroll
        for (int j = 0; j < 4; ++j)
          acc[i][j] = __builtin_amdgcn_mfma_f32_16x16x32_bf16(
              af[i], bfr[j], acc[i][j], 0, 0, 0);
    }
  }

#pragma unroll
  for (int i = 0; i < 4; ++i) {
#pragma unroll
    for (int r = 0; r < 4; ++r) {
      const int m = m0 + wm + i * 16 + quad * 4 + r;
#pragma unroll
      for (int j = 0; j < 4; ++j) {
        const int c = wn + j * 16 + l15;
        const int np = g * 128 + c;  // head-contiguous col h*64+d
        const float v = acc[i][j][r];
        if (kind == 0) {
          Qr[(size_t)m * DIMM + np] = __float2bfloat16(v * QSCALE);
        } else if (kind == 1) {
          Kr[(size_t)m * DIMM + np] = __float2bfloat16(v);
        } else {
          const int h = np >> 6, d = np & 63;
          const int b = m >> 11, s = m & (SS - 1);
          Vt[(((size_t)b * HH + h) * DKK + d) * SS + s] = __float2bfloat16(v);
        }
      }
    }
  }
}

// ---------------------------------------------------------------------------
// Output projection GEMM: out = Ar @ Wob^T. Tile 128m x 64n, BK=64, reg-dbuf
// (round-9 version).
// ---------------------------------------------------------------------------
__global__ __launch_bounds__(256) void out_gemm_kernel(
    const bf16* __restrict__ A, const bf16* __restrict__ W,
    float* __restrict__ out) {
  __shared__ __align__(16) bf16 As[128][72];
  __shared__ __align__(16) bf16 Bs[64][72];
  const int t = threadIdx.x;
  const int wave = t >> 6, lane = t & 63;
  const int quad = lane >> 4, l15 = lane & 15;
  const int wm = (wave >> 1) * 64, wn = (wave & 1) * 32;
  const int n0 = blockIdx.x * 64;
  const int m0 = blockIdx.y * 128;
  const int sr = t >> 2;
  const int sc = (t & 3) * 16;

  v8s ar[4], br[2];
  auto loadA = [&](int kc) {
#pragma unroll
    for (int rr = 0; rr < 2; ++rr) {
      const bf16* p = A + (size_t)(m0 + sr + rr * 64) * DIMM + kc + sc;
#pragma unroll
      for (int i = 0; i < 2; ++i) ar[rr * 2 + i] = ((const v8s*)p)[i];
    }
  };
  auto loadB = [&](int kc) {
    const bf16* p = W + (size_t)(n0 + sr) * DIMM + kc + sc;
#pragma unroll
    for (int i = 0; i < 2; ++i) br[i] = ((const v8s*)p)[i];
  };

  f32x4 acc[4][2] = {};
  loadA(0);
  loadB(0);
  for (int kc = 0; kc < DIMM; kc += 64) {
    __syncthreads();
#pragma unroll
    for (int rr = 0; rr < 2; ++rr) {
      *(v8s*)&As[sr + rr * 64][sc] = ar[rr * 2 + 0];
      *(v8s*)&As[sr + rr * 64][sc + 8] = ar[rr * 2 + 1];
    }
    *(v8s*)&Bs[sr][sc] = br[0];
    *(v8s*)&Bs[sr][sc + 8] = br[1];
    if (kc + 64 < DIMM) {
      loadA(kc + 64);
      loadB(kc + 64);
    }
    __syncthreads();
#pragma unroll
    for (int ks = 0; ks < 2; ++ks) {
      v8s af[4], bfr[2];
#pragma unroll
      for (int i = 0; i < 4; ++i)
        af[i] = *(const v8s*)&As[wm + i * 16 + l15][ks * 32 + quad * 8];
#pragma unroll
      for (int j = 0; j < 2; ++j)
        bfr[j] = *(const v8s*)&Bs[wn + j * 16 + l15][ks * 32 + quad * 8];
#pragma unroll
      for (int i = 0; i < 4; ++i)
#pragma unroll
        for (int j = 0; j < 2; ++j)
          acc[i][j] = __builtin_amdgcn_mfma_f32_16x16x32_bf16(
              af[i], bfr[j], acc[i][j], 0, 0, 0);
    }
  }

#pragma unroll
  for (int i = 0; i < 4; ++i) {
#pragma unroll
    for (int r = 0; r < 4; ++r) {
      const int m = m0 + wm + i * 16 + quad * 4 + r;
#pragma unroll
      for (int j = 0; j < 2; ++j) {
        const int n = n0 + wn + j * 16 + l15;
        out[(size_t)m * DIMM + n] = acc[i][j][r];
      }
    }
  }
}

// ---------------------------------------------------------------------------
// MFMA flash attention v3: 8-wave blocks (512 threads) share one Ks/Vs
// staging; per-wave body identical to the proven round-9 kernel (VGPR ~48).
// Block = 128 q rows (8 waves x 16), grid 512 -> 16 waves/CU (was 12.3).
// Q/K flat [b,s,h,d]; Vt [b,h,d,s]; static-max softmax; packed u64 mask.
// Ar bf16 [B,S,DIM] (q, d*16+h).
// ---------------------------------------------------------------------------
__global__ __launch_bounds__(512) void attn_kernel(
    const bf16* __restrict__ Qr, const bf16* __restrict__ Kr,
    const bf16* __restrict__ Vt, const unsigned long long* __restrict__ mp,
    bf16* __restrict__ Ar) {
  __shared__ __align__(16) bf16 Ks[64][72];
  __shared__ __align__(16) bf16 Vs[64][72];  // Vs[d][kk]
  __shared__ __align__(16) bf16 Ps[8][16][72];

  const int t = threadIdx.x;
  const int wave = t >> 6, lane = t & 63;
  const int quad = lane >> 4, l15 = lane & 15;

  // XCD swizzle: 16 q-tiles of one (b,h) on one XCD (4 bh-groups per XCD).
  const int bx = blockIdx.x;
  const int xcd = bx & 7, j = bx >> 3;
  const int g = (xcd << 2) | (j & 3);  // (b,h) group 0..31
  const int tile = j >> 2;             // q-tile 0..15 (128 rows each)
  const int h = g & 15, b = g >> 4;

  const int qw = tile * 128 + wave * 16;
  const size_t bhv = ((size_t)b * HH + h) * DKK;

  const bf16* qrow = Qr + ((size_t)(b * SS + qw + l15)) * DIMM + h * 64;
  const v8s aq0 = *(const v8s*)(qrow + quad * 8);
  const v8s aq1 = *(const v8s*)(qrow + 32 + quad * 8);

  f32x4 o[4] = {};
  float lsum[4] = {0.f, 0.f, 0.f, 0.f};

  // staging: 512 threads x 8 elems = 4096 = one 64x64 tile each for K and V
  const int id0 = t * 8;
  const int r0 = id0 >> 6, c0 = id0 & 63;

  for (int kt = 0; kt < 32; ++kt) {
    const int k0 = kt * 64;
    __syncthreads();
    {
      const bf16* kb = Kr + ((size_t)(b * SS + k0 + r0)) * DIMM + h * 64 + c0;
      *(v8s*)&Ks[r0][c0] = *(const v8s*)kb;
      *(v8s*)&Vs[r0][c0] = *(const v8s*)(Vt + (bhv + r0) * SS + k0 + c0);
    }
    __syncthreads();

    unsigned long long mw[4];
#pragma unroll
    for (int r = 0; r < 4; ++r)
      mw[r] = mp[((size_t)b * SS + qw + quad * 4 + r) * 32 + kt] >> l15;

    f32x4 sc[4];
#pragma unroll
    for (int n = 0; n < 4; ++n) {
      const v8s bk0 = *(const v8s*)&Ks[n * 16 + l15][quad * 8];
      const v8s bk1 = *(const v8s*)&Ks[n * 16 + l15][32 + quad * 8];
      f32x4 z = {0.f, 0.f, 0.f, 0.f};
      z = __builtin_amdgcn_mfma_f32_16x16x32_bf16(aq0, bk0, z, 0, 0, 0);
      sc[n] = __builtin_amdgcn_mfma_f32_16x16x32_bf16(aq1, bk1, z, 0, 0, 0);
    }

#pragma unroll
    for (int n = 0; n < 4; ++n)
#pragma unroll
      for (int r = 0; r < 4; ++r) {
        const bool keep = (mw[r] >> (n * 16)) & 1ULL;
        const float p = keep ? __builtin_amdgcn_exp2f(sc[n][r]) : 0.f;
        sc[n][r] = p;
        lsum[r] += p;
      }

    // P: C-layout -> LDS -> A-layout (per-wave region, in-wave ordering)
#pragma unroll
    for (int n = 0; n < 4; ++n)
#pragma unroll
      for (int r = 0; r < 4; ++r)
        Ps[wave][quad * 4 + r][n * 16 + l15] = __float2bfloat16(sc[n][r]);
    const v8s ap0 = *(const v8s*)&Ps[wave][l15][quad * 8];
    const v8s ap1 = *(const v8s*)&Ps[wave][l15][32 + quad * 8];

#pragma unroll
    for (int n = 0; n < 4; ++n) {
      const v8s bv0 = *(const v8s*)&Vs[n * 16 + l15][quad * 8];
      const v8s bv1 = *(const v8s*)&Vs[n * 16 + l15][32 + quad * 8];
      o[n] = __builtin_amdgcn_mfma_f32_16x16x32_bf16(ap0, bv0, o[n], 0, 0, 0);
      o[n] = __builtin_amdgcn_mfma_f32_16x16x32_bf16(ap1, bv1, o[n], 0, 0, 0);
    }
  }

#pragma unroll
  for (int r = 0; r < 4; ++r) {
    float l = lsum[r];
    l += __shfl_xor(l, 1);
    l += __shfl_xor(l, 2);
    l += __shfl_xor(l, 4);
    l += __shfl_xor(l, 8);
    const float inv = 1.f / l;
    const size_t row = (size_t)b * SS + qw + quad * 4 + r;
#pragma unroll
    for (int n = 0; n < 4; ++n) {
      const int d = n * 16 + l15;
      Ar[row * DIMM + d * 16 + h] = __float2bfloat16(o[n][r] * inv);
    }
  }
}

extern "C" void kernel_launch(void* const* d_in, const int* in_sizes, int n_in,
                              void* d_out, int out_size, void* d_ws,
                              size_t ws_size, hipStream_t stream) {
  const float* dec = (const float*)d_in[0];
  const float* enc = (const float*)d_in[1];
  const float* Wq = (const float*)d_in[2];
  const float* Wkv = (const float*)d_in[3];
  const float* Wo = (const float*)d_in[4];
  const int* mask = (const int*)d_in[5];
  float* out = (float*)d_out;

  // decb/Wqb live in d_out: dead scratch until out_gemm overwrites it.
  bf16* decb = (bf16*)d_out;
  bf16* Wqb = (bf16*)((char*)d_out + ((size_t)2 * SS * DIMM * 2));

  // ws layout (40.4 MB): encb 8 MiB (Ar overlays) | Wkvb 4 | Wob 2 |
  // Qr 8 | Kr 8 | Vt 8 | mp 1
  char* ws = (char*)d_ws;
  size_t off = 0;
  bf16* encb = (bf16*)(ws + off);
  bf16* Ar = (bf16*)(ws + off);   off += (size_t)2 * SS * DIMM * 2;
  bf16* Wkvb = (bf16*)(ws + off); off += (size_t)2 * DIMM * DIMM * 2;
  bf16* Wob = (bf16*)(ws + off);  off += (size_t)DIMM * DIMM * 2;
  bf16* Qr = (bf16*)(ws + off);   off += (size_t)2 * SS * DIMM * 2;
  bf16* Kr = (bf16*)(ws + off);   off += (size_t)2 * SS * DIMM * 2;
  bf16* Vt = (bf16*)(ws + off);   off += (size_t)2 * SS * DIMM * 2;
  unsigned long long* mp = (unsigned long long*)(ws + off);

  dim3 blk(256);
  convert_pack_kernel<<<dim3(1024), blk, 0, stream>>>(
      dec, enc, Wq, Wkv, Wo, mask, decb, encb, Wqb, Wkvb, Wob, mp);
  proj_gemm_kernel<<<dim3(24, 32), blk, 0, stream>>>(decb, encb, Wqb, Wkvb, Qr,
                                                     Kr, Vt);
  attn_kernel<<<dim3(512), dim3(512), 0, stream>>>(Qr, Kr, Vt, mp, Ar);
  out_gemm_kernel<<<dim3(16, 32), blk, 0, stream>>>(Ar, Wob, out);
}

// Round 13
// 274.275 us; speedup vs baseline: 1.0877x; 1.0311x over previous
//
#include <hip/hip_runtime.h>
#include <hip/hip_bf16.h>

#define BB 2
#define SS 2048
#define DIMM 1024
#define HH 16
#define DKK 64
// 0.125 (1/sqrt(DK)) * log2(e): folded into Q so softmax uses raw v_exp_f32 (2^x)
#define QSCALE 0.18033688011112042592f

using bf16 = __hip_bfloat16;
typedef __attribute__((ext_vector_type(8))) short v8s;
typedef __attribute__((ext_vector_type(4))) short v4s;
typedef __attribute__((ext_vector_type(4))) float f32x4;

__device__ __forceinline__ void cvt4(const float* __restrict__ s,
                                     bf16* __restrict__ d, int idx) {
  const float4 f = ((const float4*)s)[idx];
  bf16 t[4] = {__float2bfloat16(f.x), __float2bfloat16(f.y),
               __float2bfloat16(f.z), __float2bfloat16(f.w)};
  *(v4s*)(d + (size_t)idx * 4) = *(const v4s*)t;
}

// ---------------------------------------------------------------------------
// Fused fp32->bf16 conversion (dec, enc, Wq, Wkv, Wo) + mask bit-packing.
// decb/Wqb live in d_out (dead scratch until out_gemm overwrites it).
// ---------------------------------------------------------------------------
__global__ __launch_bounds__(256) void convert_pack_kernel(
    const float* __restrict__ dec, const float* __restrict__ enc,
    const float* __restrict__ Wq, const float* __restrict__ Wkv,
    const float* __restrict__ Wo, const int* __restrict__ mask,
    bf16* __restrict__ decb, bf16* __restrict__ encb, bf16* __restrict__ Wqb,
    bf16* __restrict__ Wkvb, bf16* __restrict__ Wob,
    unsigned long long* __restrict__ mp) {
  const int gid = blockIdx.x * 256 + threadIdx.x;  // 0..262143
  const int NT = 256 * 1024;
#pragma unroll
  for (int i = 0; i < 4; ++i) cvt4(dec, decb, gid + i * NT);
#pragma unroll
  for (int i = 0; i < 4; ++i) cvt4(enc, encb, gid + i * NT);
  cvt4(Wq, Wqb, gid);
#pragma unroll
  for (int i = 0; i < 2; ++i) cvt4(Wkv, Wkvb, gid + i * NT);
  cvt4(Wo, Wob, gid);
  const int lane = threadIdx.x & 63;
  const int wave_id = gid >> 6;  // 0..4095
  for (int i = 0; i < 32; ++i) {
    const size_t w = (size_t)wave_id * 32 + i;
    const unsigned long long bm = __ballot(mask[w * 64 + lane] != 0);
    if (lane == 0) mp[w] = bm;
  }
}

// ---------------------------------------------------------------------------
// Merged projection GEMM (round-9 reg-dbuf version — proven best at this
// shape).  Tile 128m x 128n, BK=64.  Grid (24, 32): bx>>3 = 0->Q, 1->K, 2->V.
// W rows index-permuted so output col n' = h*64+d.  Q/K store flat [b,s,h,d];
// V scatters to [b,h,d,s].
// ---------------------------------------------------------------------------
__global__ __launch_bounds__(256) void proj_gemm_kernel(
    const bf16* __restrict__ decb, const bf16* __restrict__ encb,
    const bf16* __restrict__ Wqb, const bf16* __restrict__ Wkvb,
    bf16* __restrict__ Qr, bf16* __restrict__ Kr, bf16* __restrict__ Vt) {
  __shared__ __align__(16) bf16 As[128][72];
  __shared__ __align__(16) bf16 Bs[128][72];
  const int t = threadIdx.x;
  const int wave = t >> 6, lane = t & 63;
  const int quad = lane >> 4, l15 = lane & 15;
  const int wm = (wave >> 1) * 64, wn = (wave & 1) * 64;
  const int bx = blockIdx.x;
  const int kind = bx >> 3;  // 0=Q, 1=K, 2=V
  const int g = bx & 7;      // 128-col group (2 heads)
  const int m0 = blockIdx.y * 128;

  const bf16* Asrc = (kind == 0) ? decb : encb;
  const bf16* Wsrc = (kind == 0) ? Wqb : Wkvb;

  const int sr = t >> 2;        // staging row 0..63 (and +64)
  const int sc = (t & 3) * 16;  // staging col segment
  const int wr0 = sr * 16 + g * 2 + ((kind == 2) ? DIMM : 0);      // row sr
  const int wr1 = sr * 16 + g * 2 + 1 + ((kind == 2) ? DIMM : 0);  // row sr+64

  v8s apf[4], bpf[4];
  auto loadA = [&](int kc) {
    const bf16* p0 = Asrc + (size_t)(m0 + sr) * DIMM + kc + sc;
    apf[0] = ((const v8s*)p0)[0];
    apf[1] = ((const v8s*)p0)[1];
    const bf16* p1 = Asrc + (size_t)(m0 + sr + 64) * DIMM + kc + sc;
    apf[2] = ((const v8s*)p1)[0];
    apf[3] = ((const v8s*)p1)[1];
  };
  auto loadB = [&](int kc) {
    const bf16* q0 = Wsrc + (size_t)wr0 * DIMM + kc + sc;
    bpf[0] = ((const v8s*)q0)[0];
    bpf[1] = ((const v8s*)q0)[1];
    const bf16* q1 = Wsrc + (size_t)wr1 * DIMM + kc + sc;
    bpf[2] = ((const v8s*)q1)[0];
    bpf[3] = ((const v8s*)q1)[1];
  };

  f32x4 acc[4][4] = {};
  loadA(0);
  loadB(0);

  for (int kc = 0; kc < DIMM; kc += 64) {
    __syncthreads();
    *(v8s*)&As[sr][sc] = apf[0];
    *(v8s*)&As[sr][sc + 8] = apf[1];
    *(v8s*)&As[sr + 64][sc] = apf[2];
    *(v8s*)&As[sr + 64][sc + 8] = apf[3];
    *(v8s*)&Bs[sr][sc] = bpf[0];
    *(v8s*)&Bs[sr][sc + 8] = bpf[1];
    *(v8s*)&Bs[sr + 64][sc] = bpf[2];
    *(v8s*)&Bs[sr + 64][sc + 8] = bpf[3];
    if (kc + 64 < DIMM) {
      loadA(kc + 64);
      loadB(kc + 64);
    }
    __syncthreads();
#pragma unroll
    for (int ks = 0; ks < 2; ++ks) {
      v8s af[4], bfr[4];
#pragma unroll
      for (int i = 0; i < 4; ++i)
        af[i] = *(const v8s*)&As[wm + i * 16 + l15][ks * 32 + quad * 8];
#pragma unroll
      for (int j = 0; j < 4; ++j)
        bfr[j] = *(const v8s*)&Bs[wn + j * 16 + l15][ks * 32 + quad * 8];
#pragma unroll
      for (int i = 0; i < 4; ++i)
#pragma unroll
        for (int j = 0; j < 4; ++j)
          acc[i][j] = __builtin_amdgcn_mfma_f32_16x16x32_bf16(
              af[i], bfr[j], acc[i][j], 0, 0, 0);
    }
  }

#pragma unroll
  for (int i = 0; i < 4; ++i) {
#pragma unroll
    for (int r = 0; r < 4; ++r) {
      const int m = m0 + wm + i * 16 + quad * 4 + r;
#pragma unroll
      for (int j = 0; j < 4; ++j) {
        const int c = wn + j * 16 + l15;
        const int np = g * 128 + c;  // head-contiguous col h*64+d
        const float v = acc[i][j][r];
        if (kind == 0) {
          Qr[(size_t)m * DIMM + np] = __float2bfloat16(v * QSCALE);
        } else if (kind == 1) {
          Kr[(size_t)m * DIMM + np] = __float2bfloat16(v);
        } else {
          const int h = np >> 6, d = np & 63;
          const int b = m >> 11, s = m & (SS - 1);
          Vt[(((size_t)b * HH + h) * DKK + d) * SS + s] = __float2bfloat16(v);
        }
      }
    }
  }
}

// ---------------------------------------------------------------------------
// Output projection GEMM: out = Ar @ Wob^T. Tile 128m x 64n, BK=64, reg-dbuf.
// ---------------------------------------------------------------------------
__global__ __launch_bounds__(256) void out_gemm_kernel(
    const bf16* __restrict__ A, const bf16* __restrict__ W,
    float* __restrict__ out) {
  __shared__ __align__(16) bf16 As[128][72];
  __shared__ __align__(16) bf16 Bs[64][72];
  const int t = threadIdx.x;
  const int wave = t >> 6, lane = t & 63;
  const int quad = lane >> 4, l15 = lane & 15;
  const int wm = (wave >> 1) * 64, wn = (wave & 1) * 32;
  const int n0 = blockIdx.x * 64;
  const int m0 = blockIdx.y * 128;
  const int sr = t >> 2;
  const int sc = (t & 3) * 16;

  v8s ar[4], br[2];
  auto loadA = [&](int kc) {
#pragma unroll
    for (int rr = 0; rr < 2; ++rr) {
      const bf16* p = A + (size_t)(m0 + sr + rr * 64) * DIMM + kc + sc;
#pragma unroll
      for (int i = 0; i < 2; ++i) ar[rr * 2 + i] = ((const v8s*)p)[i];
    }
  };
  auto loadB = [&](int kc) {
    const bf16* p = W + (size_t)(n0 + sr) * DIMM + kc + sc;
#pragma unroll
    for (int i = 0; i < 2; ++i) br[i] = ((const v8s*)p)[i];
  };

  f32x4 acc[4][2] = {};
  loadA(0);
  loadB(0);
  for (int kc = 0; kc < DIMM; kc += 64) {
    __syncthreads();
#pragma unroll
    for (int rr = 0; rr < 2; ++rr) {
      *(v8s*)&As[sr + rr * 64][sc] = ar[rr * 2 + 0];
      *(v8s*)&As[sr + rr * 64][sc + 8] = ar[rr * 2 + 1];
    }
    *(v8s*)&Bs[sr][sc] = br[0];
    *(v8s*)&Bs[sr][sc + 8] = br[1];
    if (kc + 64 < DIMM) {
      loadA(kc + 64);
      loadB(kc + 64);
    }
    __syncthreads();
#pragma unroll
    for (int ks = 0; ks < 2; ++ks) {
      v8s af[4], bfr[2];
#pragma unroll
      for (int i = 0; i < 4; ++i)
        af[i] = *(const v8s*)&As[wm + i * 16 + l15][ks * 32 + quad * 8];
#pragma unroll
      for (int j = 0; j < 2; ++j)
        bfr[j] = *(const v8s*)&Bs[wn + j * 16 + l15][ks * 32 + quad * 8];
#pragma unroll
      for (int i = 0; i < 4; ++i)
#pragma unroll
        for (int j = 0; j < 2; ++j)
          acc[i][j] = __builtin_amdgcn_mfma_f32_16x16x32_bf16(
              af[i], bfr[j], acc[i][j], 0, 0, 0);
    }
  }

#pragma unroll
  for (int i = 0; i < 4; ++i) {
#pragma unroll
    for (int r = 0; r < 4; ++r) {
      const int m = m0 + wm + i * 16 + quad * 4 + r;
#pragma unroll
      for (int j = 0; j < 2; ++j) {
        const int n = n0 + wn + j * 16 + l15;
        out[(size_t)m * DIMM + n] = acc[i][j][r];
      }
    }
  }
}

// ---------------------------------------------------------------------------
// MFMA flash attention v4: 8-wave blocks, LDS DOUBLE-BUFFERED K/V staging
// with register prefetch -> ONE __syncthreads per kt, staging latency hidden.
// Block = 128 q rows (8 waves x 16), grid 512, XCD swizzle.
// Q/K flat [b,s,h,d]; Vt [b,h,d,s]; static-max softmax; packed u64 mask.
// Ar bf16 [B,S,DIM] (q, d*16+h).
// ---------------------------------------------------------------------------
__global__ __launch_bounds__(512) void attn_kernel(
    const bf16* __restrict__ Qr, const bf16* __restrict__ Kr,
    const bf16* __restrict__ Vt, const unsigned long long* __restrict__ mp,
    bf16* __restrict__ Ar) {
  __shared__ __align__(16) bf16 Ks[2][64][72];
  __shared__ __align__(16) bf16 Vs[2][64][72];  // Vs[p][d][kk]
  __shared__ __align__(16) bf16 Ps[8][16][72];

  const int t = threadIdx.x;
  const int wave = t >> 6, lane = t & 63;
  const int quad = lane >> 4, l15 = lane & 15;

  // XCD swizzle: 16 q-tiles of one (b,h) on one XCD (4 bh-groups per XCD).
  const int bx = blockIdx.x;
  const int xcd = bx & 7, j = bx >> 3;
  const int g = (xcd << 2) | (j & 3);  // (b,h) group 0..31
  const int tile = j >> 2;             // q-tile 0..15 (128 rows each)
  const int h = g & 15, b = g >> 4;

  const int qw = tile * 128 + wave * 16;
  const size_t bhv = ((size_t)b * HH + h) * DKK;

  const bf16* qrow = Qr + ((size_t)(b * SS + qw + l15)) * DIMM + h * 64;
  const v8s aq0 = *(const v8s*)(qrow + quad * 8);
  const v8s aq1 = *(const v8s*)(qrow + 32 + quad * 8);

  f32x4 o[4] = {};
  float lsum[4] = {0.f, 0.f, 0.f, 0.f};

  // staging: 512 threads x 8 elems = one full 64x64 tile each for K and V
  const int id0 = t * 8;
  const int r0 = id0 >> 6, c0 = id0 & 63;

  auto loadK = [&](int kt) {
    return *(const v8s*)(Kr + ((size_t)(b * SS + kt * 64 + r0)) * DIMM +
                         h * 64 + c0);
  };
  auto loadV = [&](int kt) {
    return *(const v8s*)(Vt + (bhv + r0) * SS + kt * 64 + c0);
  };

  // prologue: stage tile 0 into buffer 0; prefetch tile 1 into regs
  v8s kreg = loadK(0), vreg = loadV(0);
  *(v8s*)&Ks[0][r0][c0] = kreg;
  *(v8s*)&Vs[0][r0][c0] = vreg;
  kreg = loadK(1);
  vreg = loadV(1);

  int p = 0;
  for (int kt = 0; kt < 32; ++kt) {
    __syncthreads();  // single barrier per kt: prior readers of buf 1-p done;
                      // writes to buf p (from kt-1) now visible
    if (kt < 31) {
      *(v8s*)&Ks[p ^ 1][r0][c0] = kreg;
      *(v8s*)&Vs[p ^ 1][r0][c0] = vreg;
      if (kt < 30) {
        kreg = loadK(kt + 2);
        vreg = loadV(kt + 2);
      }
    }

    unsigned long long mw[4];
#pragma unroll
    for (int r = 0; r < 4; ++r)
      mw[r] = mp[((size_t)b * SS + qw + quad * 4 + r) * 32 + kt] >> l15;

    f32x4 sc[4];
#pragma unroll
    for (int n = 0; n < 4; ++n) {
      const v8s bk0 = *(const v8s*)&Ks[p][n * 16 + l15][quad * 8];
      const v8s bk1 = *(const v8s*)&Ks[p][n * 16 + l15][32 + quad * 8];
      f32x4 z = {0.f, 0.f, 0.f, 0.f};
      z = __builtin_amdgcn_mfma_f32_16x16x32_bf16(aq0, bk0, z, 0, 0, 0);
      sc[n] = __builtin_amdgcn_mfma_f32_16x16x32_bf16(aq1, bk1, z, 0, 0, 0);
    }

#pragma unroll
    for (int n = 0; n < 4; ++n)
#pragma unroll
      for (int r = 0; r < 4; ++r) {
        const bool keep = (mw[r] >> (n * 16)) & 1ULL;
        const float pw = keep ? __builtin_amdgcn_exp2f(sc[n][r]) : 0.f;
        sc[n][r] = pw;
        lsum[r] += pw;
      }

    // P: C-layout -> LDS -> A-layout (per-wave region, in-wave ordering)
#pragma unroll
    for (int n = 0; n < 4; ++n)
#pragma unroll
      for (int r = 0; r < 4; ++r)
        Ps[wave][quad * 4 + r][n * 16 + l15] = __float2bfloat16(sc[n][r]);
    const v8s ap0 = *(const v8s*)&Ps[wave][l15][quad * 8];
    const v8s ap1 = *(const v8s*)&Ps[wave][l15][32 + quad * 8];

#pragma unroll
    for (int n = 0; n < 4; ++n) {
      const v8s bv0 = *(const v8s*)&Vs[p][n * 16 + l15][quad * 8];
      const v8s bv1 = *(const v8s*)&Vs[p][n * 16 + l15][32 + quad * 8];
      o[n] = __builtin_amdgcn_mfma_f32_16x16x32_bf16(ap0, bv0, o[n], 0, 0, 0);
      o[n] = __builtin_amdgcn_mfma_f32_16x16x32_bf16(ap1, bv1, o[n], 0, 0, 0);
    }
    p ^= 1;
  }

#pragma unroll
  for (int r = 0; r < 4; ++r) {
    float l = lsum[r];
    l += __shfl_xor(l, 1);
    l += __shfl_xor(l, 2);
    l += __shfl_xor(l, 4);
    l += __shfl_xor(l, 8);
    const float inv = 1.f / l;
    const size_t row = (size_t)b * SS + qw + quad * 4 + r;
#pragma unroll
    for (int n = 0; n < 4; ++n) {
      const int d = n * 16 + l15;
      Ar[row * DIMM + d * 16 + h] = __float2bfloat16(o[n][r] * inv);
    }
  }
}

extern "C" void kernel_launch(void* const* d_in, const int* in_sizes, int n_in,
                              void* d_out, int out_size, void* d_ws,
                              size_t ws_size, hipStream_t stream) {
  const float* dec = (const float*)d_in[0];
  const float* enc = (const float*)d_in[1];
  const float* Wq = (const float*)d_in[2];
  const float* Wkv = (const float*)d_in[3];
  const float* Wo = (const float*)d_in[4];
  const int* mask = (const int*)d_in[5];
  float* out = (float*)d_out;

  // decb/Wqb live in d_out: dead scratch until out_gemm overwrites it.
  bf16* decb = (bf16*)d_out;
  bf16* Wqb = (bf16*)((char*)d_out + ((size_t)2 * SS * DIMM * 2));

  // ws layout (40.4 MB): encb 8 MiB (Ar overlays) | Wkvb 4 | Wob 2 |
  // Qr 8 | Kr 8 | Vt 8 | mp 1
  char* ws = (char*)d_ws;
  size_t off = 0;
  bf16* encb = (bf16*)(ws + off);
  bf16* Ar = (bf16*)(ws + off);   off += (size_t)2 * SS * DIMM * 2;
  bf16* Wkvb = (bf16*)(ws + off); off += (size_t)2 * DIMM * DIMM * 2;
  bf16* Wob = (bf16*)(ws + off);  off += (size_t)DIMM * DIMM * 2;
  bf16* Qr = (bf16*)(ws + off);   off += (size_t)2 * SS * DIMM * 2;
  bf16* Kr = (bf16*)(ws + off);   off += (size_t)2 * SS * DIMM * 2;
  bf16* Vt = (bf16*)(ws + off);   off += (size_t)2 * SS * DIMM * 2;
  unsigned long long* mp = (unsigned long long*)(ws + off);

  dim3 blk(256);
  convert_pack_kernel<<<dim3(1024), blk, 0, stream>>>(
      dec, enc, Wq, Wkv, Wo, mask, decb, encb, Wqb, Wkvb, Wob, mp);
  proj_gemm_kernel<<<dim3(24, 32), blk, 0, stream>>>(decb, encb, Wqb, Wkvb, Qr,
                                                     Kr, Vt);
  attn_kernel<<<dim3(512), dim3(512), 0, stream>>>(Qr, Kr, Vt, mp, Ar);
  out_gemm_kernel<<<dim3(16, 32), blk, 0, stream>>>(Ar, Wob, out);
}

// Round 14
// 255.499 us; speedup vs baseline: 1.1676x; 1.0735x over previous
//
#include <hip/hip_runtime.h>
#include <hip/hip_bf16.h>

#define BB 2
#define SS 2048
#define DIMM 1024
#define HH 16
#define DKK 64
// 0.125 (1/sqrt(DK)) * log2(e): folded into Q so softmax uses raw v_exp_f32 (2^x)
#define QSCALE 0.18033688011112042592f

using bf16 = __hip_bfloat16;
typedef __attribute__((ext_vector_type(8))) short v8s;
typedef __attribute__((ext_vector_type(4))) short v4s;
typedef __attribute__((ext_vector_type(4))) float f32x4;

__device__ __forceinline__ void cvt4(const float* __restrict__ s,
                                     bf16* __restrict__ d, int idx) {
  const float4 f = ((const float4*)s)[idx];
  bf16 t[4] = {__float2bfloat16(f.x), __float2bfloat16(f.y),
               __float2bfloat16(f.z), __float2bfloat16(f.w)};
  *(v4s*)(d + (size_t)idx * 4) = *(const v4s*)t;
}

// ---------------------------------------------------------------------------
// Fused fp32->bf16 conversion (dec, enc, Wq, Wkv, Wo) + mask bit-packing.
// Wo is converted with PERMUTED columns: Wob[n][h*64+d] = Wo[n][d*16+h], so
// out_gemm can consume the flat [q][h*64+d] Ar layout.
// decb/Wqb live in d_out (dead scratch until out_gemm overwrites it).
// ---------------------------------------------------------------------------
__global__ __launch_bounds__(256) void convert_pack_kernel(
    const float* __restrict__ dec, const float* __restrict__ enc,
    const float* __restrict__ Wq, const float* __restrict__ Wkv,
    const float* __restrict__ Wo, const int* __restrict__ mask,
    bf16* __restrict__ decb, bf16* __restrict__ encb, bf16* __restrict__ Wqb,
    bf16* __restrict__ Wkvb, bf16* __restrict__ Wob,
    unsigned long long* __restrict__ mp) {
  const int gid = blockIdx.x * 256 + threadIdx.x;  // 0..262143
  const int NT = 256 * 1024;
#pragma unroll
  for (int i = 0; i < 4; ++i) cvt4(dec, decb, gid + i * NT);
#pragma unroll
  for (int i = 0; i < 4; ++i) cvt4(enc, encb, gid + i * NT);
  cvt4(Wq, Wqb, gid);
#pragma unroll
  for (int i = 0; i < 2; ++i) cvt4(Wkv, Wkvb, gid + i * NT);
  // Wo with column permutation c' = h*64+d  <-  c = d*16+h
  {
    const int n = gid >> 8;          // row 0..1023
    const int c4 = (gid & 255) * 4;  // dest col base (4 consecutive d)
    const int h = c4 >> 6, d0 = c4 & 63;
    const float* src = Wo + (size_t)n * DIMM + h;
    bf16 t[4];
#pragma unroll
    for (int i2 = 0; i2 < 4; ++i2)
      t[i2] = __float2bfloat16(src[(d0 + i2) * 16]);
    *(v4s*)(Wob + (size_t)n * DIMM + c4) = *(const v4s*)t;
  }
  const int lane = threadIdx.x & 63;
  const int wave_id = gid >> 6;  // 0..4095
  for (int i = 0; i < 32; ++i) {
    const size_t w = (size_t)wave_id * 32 + i;
    const unsigned long long bm = __ballot(mask[w * 64 + lane] != 0);
    if (lane == 0) mp[w] = bm;
  }
}

// ---------------------------------------------------------------------------
// Merged projection GEMM, uniform bf16, tile 128x128, BK=64, reg-dbuf.
// Grid (24, 32): kind = bx>>3: 0 -> Q, 1 -> K, 2 -> V;  g = bx&7.
// Q/K: A = activations rows (m = token), B = W permuted rows (n' = h*64+d),
//      store flat [b,s,h,d] coalesced (Q prescaled).
// V:   TRANSPOSED formulation — A = Wv permuted rows (m = d-dim, 2 heads),
//      B = encb rows (n = token), C[m=d][n=s] stores Vt[b,h,d,s] with lanes
//      -> consecutive s (coalesced; kills the old 4KB-stride 2B scatter).
// ---------------------------------------------------------------------------
__global__ __launch_bounds__(256) void proj_gemm_kernel(
    const bf16* __restrict__ decb, const bf16* __restrict__ encb,
    const bf16* __restrict__ Wqb, const bf16* __restrict__ Wkvb,
    bf16* __restrict__ Qr, bf16* __restrict__ Kr, bf16* __restrict__ Vt) {
  __shared__ __align__(16) bf16 As[128][72];
  __shared__ __align__(16) bf16 Bs[128][72];
  const int t = threadIdx.x;
  const int wave = t >> 6, lane = t & 63;
  const int quad = lane >> 4, l15 = lane & 15;
  const int wm = (wave >> 1) * 64, wn = (wave & 1) * 64;
  const int bx = blockIdx.x;
  const int kind = bx >> 3;  // 0=Q, 1=K, 2=V
  const int g = bx & 7;      // 128-col group (2 heads)
  const int m0 = blockIdx.y * 128;

  const int sr = t >> 2;        // staging row 0..63 (and +64)
  const int sc = (t & 3) * 16;  // staging col segment
  // permuted W row for tile rows sr / sr+64 of the W-side 128-row tile
  const int voff = (kind == 2) ? DIMM : 0;
  const int wr0 = sr * 16 + g * 2 + voff;
  const int wr1 = sr * 16 + g * 2 + 1 + voff;

  // A-side / B-side global row pointers (swap roles for V)
  const bf16* arow0;
  const bf16* arow1;
  const bf16* brow0;
  const bf16* brow1;
  if (kind == 0) {
    arow0 = decb + (size_t)(m0 + sr) * DIMM;
    arow1 = decb + (size_t)(m0 + sr + 64) * DIMM;
    brow0 = Wqb + (size_t)wr0 * DIMM;
    brow1 = Wqb + (size_t)wr1 * DIMM;
  } else if (kind == 1) {
    arow0 = encb + (size_t)(m0 + sr) * DIMM;
    arow1 = encb + (size_t)(m0 + sr + 64) * DIMM;
    brow0 = Wkvb + (size_t)wr0 * DIMM;
    brow1 = Wkvb + (size_t)wr1 * DIMM;
  } else {
    arow0 = Wkvb + (size_t)wr0 * DIMM;
    arow1 = Wkvb + (size_t)wr1 * DIMM;
    brow0 = encb + (size_t)(m0 + sr) * DIMM;
    brow1 = encb + (size_t)(m0 + sr + 64) * DIMM;
  }

  v8s apf[4], bpf[4];
  auto loadAB = [&](int kc) {
    apf[0] = ((const v8s*)(arow0 + kc + sc))[0];
    apf[1] = ((const v8s*)(arow0 + kc + sc))[1];
    apf[2] = ((const v8s*)(arow1 + kc + sc))[0];
    apf[3] = ((const v8s*)(arow1 + kc + sc))[1];
    bpf[0] = ((const v8s*)(brow0 + kc + sc))[0];
    bpf[1] = ((const v8s*)(brow0 + kc + sc))[1];
    bpf[2] = ((const v8s*)(brow1 + kc + sc))[0];
    bpf[3] = ((const v8s*)(brow1 + kc + sc))[1];
  };

  f32x4 acc[4][4] = {};
  loadAB(0);

  for (int kc = 0; kc < DIMM; kc += 64) {
    __syncthreads();
    *(v8s*)&As[sr][sc] = apf[0];
    *(v8s*)&As[sr][sc + 8] = apf[1];
    *(v8s*)&As[sr + 64][sc] = apf[2];
    *(v8s*)&As[sr + 64][sc + 8] = apf[3];
    *(v8s*)&Bs[sr][sc] = bpf[0];
    *(v8s*)&Bs[sr][sc + 8] = bpf[1];
    *(v8s*)&Bs[sr + 64][sc] = bpf[2];
    *(v8s*)&Bs[sr + 64][sc + 8] = bpf[3];
    if (kc + 64 < DIMM) loadAB(kc + 64);
    __syncthreads();
#pragma unroll
    for (int ks = 0; ks < 2; ++ks) {
      v8s af[4], bfr[4];
#pragma unroll
      for (int i = 0; i < 4; ++i)
        af[i] = *(const v8s*)&As[wm + i * 16 + l15][ks * 32 + quad * 8];
#pragma unroll
      for (int j = 0; j < 4; ++j)
        bfr[j] = *(const v8s*)&Bs[wn + j * 16 + l15][ks * 32 + quad * 8];
#pragma unroll
      for (int i = 0; i < 4; ++i)
#pragma unroll
        for (int j = 0; j < 4; ++j)
          acc[i][j] = __builtin_amdgcn_mfma_f32_16x16x32_bf16(
              af[i], bfr[j], acc[i][j], 0, 0, 0);
    }
  }

#pragma unroll
  for (int i = 0; i < 4; ++i) {
#pragma unroll
    for (int r = 0; r < 4; ++r) {
      const int mm = wm + i * 16 + quad * 4 + r;  // tile-m 0..127
#pragma unroll
      for (int j = 0; j < 4; ++j) {
        const int nn = wn + j * 16 + l15;  // tile-n 0..127
        const float v = acc[i][j][r];
        if (kind == 0) {
          Qr[(size_t)(m0 + mm) * DIMM + g * 128 + nn] =
              __float2bfloat16(v * QSCALE);
        } else if (kind == 1) {
          Kr[(size_t)(m0 + mm) * DIMM + g * 128 + nn] = __float2bfloat16(v);
        } else {
          const int h = g * 2 + (mm >> 6), d = mm & 63;
          const int sn = m0 + nn;
          const int b = sn >> 11, s = sn & (SS - 1);
          Vt[(((size_t)b * HH + h) * DKK + d) * SS + s] = __float2bfloat16(v);
        }
      }
    }
  }
}

// ---------------------------------------------------------------------------
// Output projection GEMM: out = Ar @ Wob^T (Wob cols pre-permuted to match
// Ar's flat [q][h*64+d] layout). Tile 128m x 64n, BK=64, reg-dbuf.
// ---------------------------------------------------------------------------
__global__ __launch_bounds__(256) void out_gemm_kernel(
    const bf16* __restrict__ A, const bf16* __restrict__ W,
    float* __restrict__ out) {
  __shared__ __align__(16) bf16 As[128][72];
  __shared__ __align__(16) bf16 Bs[64][72];
  const int t = threadIdx.x;
  const int wave = t >> 6, lane = t & 63;
  const int quad = lane >> 4, l15 = lane & 15;
  const int wm = (wave >> 1) * 64, wn = (wave & 1) * 32;
  const int n0 = blockIdx.x * 64;
  const int m0 = blockIdx.y * 128;
  const int sr = t >> 2;
  const int sc = (t & 3) * 16;

  v8s ar[4], br[2];
  auto loadA = [&](int kc) {
#pragma unroll
    for (int rr = 0; rr < 2; ++rr) {
      const bf16* p = A + (size_t)(m0 + sr + rr * 64) * DIMM + kc + sc;
#pragma unroll
      for (int i = 0; i < 2; ++i) ar[rr * 2 + i] = ((const v8s*)p)[i];
    }
  };
  auto loadB = [&](int kc) {
    const bf16* p = W + (size_t)(n0 + sr) * DIMM + kc + sc;
#pragma unroll
    for (int i = 0; i < 2; ++i) br[i] = ((const v8s*)p)[i];
  };

  f32x4 acc[4][2] = {};
  loadA(0);
  loadB(0);
  for (int kc = 0; kc < DIMM; kc += 64) {
    __syncthreads();
#pragma unroll
    for (int rr = 0; rr < 2; ++rr) {
      *(v8s*)&As[sr + rr * 64][sc] = ar[rr * 2 + 0];
      *(v8s*)&As[sr + rr * 64][sc + 8] = ar[rr * 2 + 1];
    }
    *(v8s*)&Bs[sr][sc] = br[0];
    *(v8s*)&Bs[sr][sc + 8] = br[1];
    if (kc + 64 < DIMM) {
      loadA(kc + 64);
      loadB(kc + 64);
    }
    __syncthreads();
#pragma unroll
    for (int ks = 0; ks < 2; ++ks) {
      v8s af[4], bfr[2];
#pragma unroll
      for (int i = 0; i < 4; ++i)
        af[i] = *(const v8s*)&As[wm + i * 16 + l15][ks * 32 + quad * 8];
#pragma unroll
      for (int j = 0; j < 2; ++j)
        bfr[j] = *(const v8s*)&Bs[wn + j * 16 + l15][ks * 32 + quad * 8];
#pragma unroll
      for (int i = 0; i < 4; ++i)
#pragma unroll
        for (int j = 0; j < 2; ++j)
          acc[i][j] = __builtin_amdgcn_mfma_f32_16x16x32_bf16(
              af[i], bfr[j], acc[i][j], 0, 0, 0);
    }
  }

#pragma unroll
  for (int i = 0; i < 4; ++i) {
#pragma unroll
    for (int r = 0; r < 4; ++r) {
      const int m = m0 + wm + i * 16 + quad * 4 + r;
#pragma unroll
      for (int j = 0; j < 2; ++j) {
        const int n = n0 + wn + j * 16 + l15;
        out[(size_t)m * DIMM + n] = acc[i][j][r];
      }
    }
  }
}

// ---------------------------------------------------------------------------
// MFMA flash attention v4 (R13 body) with FLAT Ar store [q][h*64+d]
// (lanes -> consecutive addresses; was d*16+h stride-32B scatter, 4x write
// amplification).  8-wave blocks, LDS double-buffer, one barrier per kt.
// ---------------------------------------------------------------------------
__global__ __launch_bounds__(512) void attn_kernel(
    const bf16* __restrict__ Qr, const bf16* __restrict__ Kr,
    const bf16* __restrict__ Vt, const unsigned long long* __restrict__ mp,
    bf16* __restrict__ Ar) {
  __shared__ __align__(16) bf16 Ks[2][64][72];
  __shared__ __align__(16) bf16 Vs[2][64][72];  // Vs[p][d][kk]
  __shared__ __align__(16) bf16 Ps[8][16][72];

  const int t = threadIdx.x;
  const int wave = t >> 6, lane = t & 63;
  const int quad = lane >> 4, l15 = lane & 15;

  const int bx = blockIdx.x;
  const int xcd = bx & 7, j = bx >> 3;
  const int g = (xcd << 2) | (j & 3);  // (b,h) group 0..31
  const int tile = j >> 2;             // q-tile 0..15 (128 rows each)
  const int h = g & 15, b = g >> 4;

  const int qw = tile * 128 + wave * 16;
  const size_t bhv = ((size_t)b * HH + h) * DKK;

  const bf16* qrow = Qr + ((size_t)(b * SS + qw + l15)) * DIMM + h * 64;
  const v8s aq0 = *(const v8s*)(qrow + quad * 8);
  const v8s aq1 = *(const v8s*)(qrow + 32 + quad * 8);

  f32x4 o[4] = {};
  float lsum[4] = {0.f, 0.f, 0.f, 0.f};

  const int id0 = t * 8;
  const int r0 = id0 >> 6, c0 = id0 & 63;

  auto loadK = [&](int kt) {
    return *(const v8s*)(Kr + ((size_t)(b * SS + kt * 64 + r0)) * DIMM +
                         h * 64 + c0);
  };
  auto loadV = [&](int kt) {
    return *(const v8s*)(Vt + (bhv + r0) * SS + kt * 64 + c0);
  };

  v8s kreg = loadK(0), vreg = loadV(0);
  *(v8s*)&Ks[0][r0][c0] = kreg;
  *(v8s*)&Vs[0][r0][c0] = vreg;
  kreg = loadK(1);
  vreg = loadV(1);

  int p = 0;
  for (int kt = 0; kt < 32; ++kt) {
    __syncthreads();
    if (kt < 31) {
      *(v8s*)&Ks[p ^ 1][r0][c0] = kreg;
      *(v8s*)&Vs[p ^ 1][r0][c0] = vreg;
      if (kt < 30) {
        kreg = loadK(kt + 2);
        vreg = loadV(kt + 2);
      }
    }

    unsigned long long mw[4];
#pragma unroll
    for (int r = 0; r < 4; ++r)
      mw[r] = mp[((size_t)b * SS + qw + quad * 4 + r) * 32 + kt] >> l15;

    f32x4 sc[4];
#pragma unroll
    for (int n = 0; n < 4; ++n) {
      const v8s bk0 = *(const v8s*)&Ks[p][n * 16 + l15][quad * 8];
      const v8s bk1 = *(const v8s*)&Ks[p][n * 16 + l15][32 + quad * 8];
      f32x4 z = {0.f, 0.f, 0.f, 0.f};
      z = __builtin_amdgcn_mfma_f32_16x16x32_bf16(aq0, bk0, z, 0, 0, 0);
      sc[n] = __builtin_amdgcn_mfma_f32_16x16x32_bf16(aq1, bk1, z, 0, 0, 0);
    }

#pragma unroll
    for (int n = 0; n < 4; ++n)
#pragma unroll
      for (int r = 0; r < 4; ++r) {
        const bool keep = (mw[r] >> (n * 16)) & 1ULL;
        const float pw = keep ? __builtin_amdgcn_exp2f(sc[n][r]) : 0.f;
        sc[n][r] = pw;
        lsum[r] += pw;
      }

#pragma unroll
    for (int n = 0; n < 4; ++n)
#pragma unroll
      for (int r = 0; r < 4; ++r)
        Ps[wave][quad * 4 + r][n * 16 + l15] = __float2bfloat16(sc[n][r]);
    const v8s ap0 = *(const v8s*)&Ps[wave][l15][quad * 8];
    const v8s ap1 = *(const v8s*)&Ps[wave][l15][32 + quad * 8];

#pragma unroll
    for (int n = 0; n < 4; ++n) {
      const v8s bv0 = *(const v8s*)&Vs[p][n * 16 + l15][quad * 8];
      const v8s bv1 = *(const v8s*)&Vs[p][n * 16 + l15][32 + quad * 8];
      o[n] = __builtin_amdgcn_mfma_f32_16x16x32_bf16(ap0, bv0, o[n], 0, 0, 0);
      o[n] = __builtin_amdgcn_mfma_f32_16x16x32_bf16(ap1, bv1, o[n], 0, 0, 0);
    }
    p ^= 1;
  }

#pragma unroll
  for (int r = 0; r < 4; ++r) {
    float l = lsum[r];
    l += __shfl_xor(l, 1);
    l += __shfl_xor(l, 2);
    l += __shfl_xor(l, 4);
    l += __shfl_xor(l, 8);
    const float inv = 1.f / l;
    const size_t row = (size_t)b * SS + qw + quad * 4 + r;
#pragma unroll
    for (int n = 0; n < 4; ++n) {
      // FLAT store: col = h*64 + n*16 + l15 (lanes consecutive)
      Ar[row * DIMM + h * 64 + n * 16 + l15] = __float2bfloat16(o[n][r] * inv);
    }
  }
}

extern "C" void kernel_launch(void* const* d_in, const int* in_sizes, int n_in,
                              void* d_out, int out_size, void* d_ws,
                              size_t ws_size, hipStream_t stream) {
  const float* dec = (const float*)d_in[0];
  const float* enc = (const float*)d_in[1];
  const float* Wq = (const float*)d_in[2];
  const float* Wkv = (const float*)d_in[3];
  const float* Wo = (const float*)d_in[4];
  const int* mask = (const int*)d_in[5];
  float* out = (float*)d_out;

  // decb/Wqb live in d_out: dead scratch until out_gemm overwrites it.
  bf16* decb = (bf16*)d_out;
  bf16* Wqb = (bf16*)((char*)d_out + ((size_t)2 * SS * DIMM * 2));

  // ws layout (40.4 MB): encb 8 MiB (Ar overlays) | Wkvb 4 | Wob 2 |
  // Qr 8 | Kr 8 | Vt 8 | mp 1
  char* ws = (char*)d_ws;
  size_t off = 0;
  bf16* encb = (bf16*)(ws + off);
  bf16* Ar = (bf16*)(ws + off);   off += (size_t)2 * SS * DIMM * 2;
  bf16* Wkvb = (bf16*)(ws + off); off += (size_t)2 * DIMM * DIMM * 2;
  bf16* Wob = (bf16*)(ws + off);  off += (size_t)DIMM * DIMM * 2;
  bf16* Qr = (bf16*)(ws + off);   off += (size_t)2 * SS * DIMM * 2;
  bf16* Kr = (bf16*)(ws + off);   off += (size_t)2 * SS * DIMM * 2;
  bf16* Vt = (bf16*)(ws + off);   off += (size_t)2 * SS * DIMM * 2;
  unsigned long long* mp = (unsigned long long*)(ws + off);

  dim3 blk(256);
  convert_pack_kernel<<<dim3(1024), blk, 0, stream>>>(
      dec, enc, Wq, Wkv, Wo, mask, decb, encb, Wqb, Wkvb, Wob, mp);
  proj_gemm_kernel<<<dim3(24, 32), blk, 0, stream>>>(decb, encb, Wqb, Wkvb, Qr,
                                                     Kr, Vt);
  attn_kernel<<<dim3(512), dim3(512), 0, stream>>>(Qr, Kr, Vt, mp, Ar);
  out_gemm_kernel<<<dim3(16, 32), blk, 0, stream>>>(Ar, Wob, out);
}